// Round 1
// baseline (1142.792 us; speedup 1.0000x reference)
//
#include <hip/hip_runtime.h>

#define NB 1024
#define DS1 25
#define DS2 10
#define DF 128

// One block per b (1024 blocks x 256 threads).
// LDS: Xs rows 0..24 = h1[s1], row 25 = h0 (rows 26,27 zero pad)
//      M2 rows 0..24 = mean_s2(h2[s1]), row 25 = mean_s1(h1)
// Layer-1 batched matmul over 26 rows handles n1[0..24] AND n0 (row 25) in one pass.
__global__ __launch_bounds__(256, 4)
void sage_fused_kernel(const float* __restrict__ features,
                       const float* __restrict__ w_self0,
                       const float* __restrict__ w_neigh0,
                       const float* __restrict__ w_self1,
                       const float* __restrict__ w_neigh1,
                       const int* __restrict__ samples0,
                       const int* __restrict__ samples1,
                       const int* __restrict__ samples2,
                       float* __restrict__ out)
{
    __shared__ float Xs[28][DF];     // 14.3 KB
    __shared__ float M2[28][DF];     // 14.3 KB
    __shared__ float Npart[4][256];  // 4 KB  (cross-wave reduction scratch)
    __shared__ float n0s[256];       // 1 KB
    __shared__ float N1s[256];       // 1 KB
    // total ~34.75 KB -> 4 blocks/CU by LDS

    const int b = blockIdx.x;
    const int t = threadIdx.x;
    const int c = t & 127;   // feature column
    const int h = t >> 7;    // half-block 0/1

    // ---- gather phase ----
    if (h == 0) {
        const int s0 = samples0[b];
        Xs[25][c] = features[(size_t)s0 * DF + c];
        Xs[26][c] = 0.f; Xs[27][c] = 0.f;
        M2[26][c] = 0.f; M2[27][c] = 0.f;
    }
    // each half handles alternating s1; 10 independent gathers per iteration
    for (int s1 = h; s1 < DS1; s1 += 2) {
        const int i1 = samples1[b * DS1 + s1];
        const int* i2 = samples2 + (size_t)(b * DS1 + s1) * DS2;
        float p = 0.f;
        #pragma unroll
        for (int j = 0; j < DS2; ++j)
            p += features[(size_t)i2[j] * DF + c];
        M2[s1][c] = p * 0.1f;                          // mean over S2
        Xs[s1][c] = features[(size_t)i1 * DF + c];     // h1 row
    }
    __syncthreads();

    // mean over s1 of h1 -> M2[25]
    if (h == 0) {
        float s = 0.f;
        #pragma unroll
        for (int r = 0; r < DS1; ++r) s += Xs[r][c];
        M2[25][c] = s * (1.0f / 25.0f);
    }
    __syncthreads();

    // ---- layer-1 batched matmul: 26 rows x 256 cols, K=128 ----
    const int w = t >> 6;                 // wave id: rows w, w+4, ..., (R=7)
    const int l = t & 63;                 // lane
    const int half = l >> 5;              // 0: self-path (Xs,Ws0)  1: neigh (M2,Wn0)
    const int co = (l & 31) * 4;          // col within the 128-wide half
    const float* __restrict__ W1 = half ? w_neigh0 : w_self0;

    float acc[7][4];
    #pragma unroll
    for (int j = 0; j < 7; ++j) {
        #pragma unroll
        for (int cc = 0; cc < 4; ++cc) acc[j][cc] = 0.f;
    }

    for (int kb = 0; kb < 32; ++kb) {
        float4 xv[7];
        #pragma unroll
        for (int j = 0; j < 7; ++j) {
            const int r = w + 4 * j;                 // up to 27 (padded rows are zero)
            const float* row = half ? &M2[r][0] : &Xs[r][0];
            xv[j] = *(const float4*)(row + kb * 4);  // broadcast ds_read_b128
        }
        #pragma unroll
        for (int kk = 0; kk < 4; ++kk) {
            const float4 wv = *(const float4*)(W1 + (kb * 4 + kk) * DF + co);
            #pragma unroll
            for (int j = 0; j < 7; ++j) {
                const float x = ((const float*)&xv[j])[kk];
                acc[j][0] = fmaf(x, wv.x, acc[j][0]);
                acc[j][1] = fmaf(x, wv.y, acc[j][1]);
                acc[j][2] = fmaf(x, wv.z, acc[j][2]);
                acc[j][3] = fmaf(x, wv.w, acc[j][3]);
            }
        }
    }

    // relu; rows <25 -> N1 partial sum; row 25 -> n0
    const int ocol = half * 128 + co;
    float pn[4] = {0.f, 0.f, 0.f, 0.f};
    #pragma unroll
    for (int j = 0; j < 7; ++j) {
        const int r = w + 4 * j;
        #pragma unroll
        for (int cc = 0; cc < 4; ++cc) {
            const float v = fmaxf(acc[j][cc], 0.f);
            if (r < 25) pn[cc] += v;
            else if (r == 25) n0s[ocol + cc] = v;   // only wave 1, j==6
        }
    }
    #pragma unroll
    for (int cc = 0; cc < 4; ++cc) Npart[w][ocol + cc] = pn[cc];
    __syncthreads();

    N1s[t] = (Npart[0][t] + Npart[1][t] + Npart[2][t] + Npart[3][t]) * (1.0f / 25.0f);
    __syncthreads();

    // ---- layer-2: out = relu(concat(n0 @ Ws1, N1mean @ Wn1)), K=256 split over waves ----
    const float* __restrict__ W2 = half ? w_neigh1 : w_self1;
    const float* __restrict__ X2 = half ? N1s : n0s;
    float a2[4] = {0.f, 0.f, 0.f, 0.f};
    #pragma unroll
    for (int kb = 0; kb < 16; ++kb) {
        const int k0 = w * 64 + kb * 4;
        const float4 x4 = *(const float4*)(X2 + k0);
        #pragma unroll
        for (int kk = 0; kk < 4; ++kk) {
            const float4 wv = *(const float4*)(W2 + (k0 + kk) * 128 + co);
            const float x = ((const float*)&x4)[kk];
            a2[0] = fmaf(x, wv.x, a2[0]);
            a2[1] = fmaf(x, wv.y, a2[1]);
            a2[2] = fmaf(x, wv.z, a2[2]);
            a2[3] = fmaf(x, wv.w, a2[3]);
        }
    }
    #pragma unroll
    for (int cc = 0; cc < 4; ++cc) Npart[w][ocol + cc] = a2[cc];
    __syncthreads();

    const float v = Npart[0][t] + Npart[1][t] + Npart[2][t] + Npart[3][t];
    out[(size_t)b * 256 + t] = fmaxf(v, 0.f);
}

extern "C" void kernel_launch(void* const* d_in, const int* in_sizes, int n_in,
                              void* d_out, int out_size, void* d_ws, size_t ws_size,
                              hipStream_t stream) {
    const float* features = (const float*)d_in[0];
    const float* w_self0  = (const float*)d_in[1];
    const float* w_neigh0 = (const float*)d_in[2];
    const float* w_self1  = (const float*)d_in[3];
    const float* w_neigh1 = (const float*)d_in[4];
    const int* samples0 = (const int*)d_in[5];
    const int* samples1 = (const int*)d_in[6];
    const int* samples2 = (const int*)d_in[7];
    float* out = (float*)d_out;

    sage_fused_kernel<<<dim3(NB), dim3(256), 0, stream>>>(
        features, w_self0, w_neigh0, w_self1, w_neigh1,
        samples0, samples1, samples2, out);
}